// Round 6
// baseline (141.837 us; speedup 1.0000x reference)
//
#include <hip/hip_runtime.h>

#define NRAYS 8192
#define NS    256
#define HID   64
#define RPB   4      // rays per block, one wave per ray
#define NSP   260    // padded diff row: slots 0..256 used, 16B-aligned stride

__global__ __launch_bounds__(256) void vr_kernel(
    const float* __restrict__ ray_start,
    const float* __restrict__ ray_dir,
    const float* __restrict__ sampled_depth,
    const float* __restrict__ sampled_dists,
    const int*   __restrict__ sampled_idx,
    const float* __restrict__ W1,
    const float* __restrict__ b1,
    const float* __restrict__ w_sigma,
    const float* __restrict__ W_rgb,
    const float* __restrict__ W_dir,
    const float* __restrict__ b_rgb,
    float* __restrict__ out)
{
    __shared__ __align__(16) float sdep[RPB][NS];
    __shared__ __align__(16) float diff[RPB][8][NSP];

    const int t    = threadIdx.x;
    const int lane = t & 63;
    const int wv   = t >> 6;                 // wave = ray slot
    const int ray  = blockIdx.x * RPB + wv;

    // this lane owns samples 4*lane .. 4*lane+3 (contiguous)
    const size_t rbase = (size_t)ray * NS;
    const float4 dep = ((const float4*)(sampled_depth + rbase))[lane];
    const float4 dst = ((const float4*)(sampled_dists + rbase))[lane];
    const int4  vidx = ((const int4*)(sampled_idx + rbase))[lane];

    // stage depths for binary search; zero the difference arrays
    ((float4*)&sdep[wv][0])[lane] = dep;
    {
        float4* dz = (float4*)&diff[wv][0][0];
        const float4 z4 = make_float4(0.f, 0.f, 0.f, 0.f);
#pragma unroll
        for (int i = 0; i < 9; ++i) {
            const int idx = lane + 64 * i;
            if (idx < (8 * NSP) / 4) dz[idx] = z4;   // 520 float4 slots per ray
        }
    }
    __syncthreads();

    const float ox = ray_start[ray*3+0], oy = ray_start[ray*3+1], oz = ray_start[ray*3+2];
    const float dxr = ray_dir[ray*3+0], dyr = ray_dir[ray*3+1], dzr = ray_dir[ray*3+2];

    // per-ray view-dependent rgb bias (wave-uniform)
    const float dwr = fmaf(dxr, W_dir[0], fmaf(dyr, W_dir[3], fmaf(dzr, W_dir[6], b_rgb[0])));
    const float dwg = fmaf(dxr, W_dir[1], fmaf(dyr, W_dir[4], fmaf(dzr, W_dir[7], b_rgb[1])));
    const float dwb = fmaf(dxr, W_dir[2], fmaf(dyr, W_dir[5], fmaf(dzr, W_dir[8], b_rgb[2])));

    // ---- phase B: lane h = hidden unit; knee + scatter into diff arrays ----
    {
        const int h = lane;
        const float w0 = W1[h], w1 = W1[HID + h], w2 = W1[2*HID + h];
        const float A = fmaf(w0, ox, fmaf(w1, oy, fmaf(w2, oz, b1[h])));
        const float B = fmaf(w0, dxr, fmaf(w1, dyr, w2 * dzr));
        const float ws = w_sigma[h];
        const float wr = W_rgb[h*3+0], wg = W_rgb[h*3+1], wq = W_rgb[h*3+2];
        const float v0 = A*ws, v1 = B*ws, v2 = A*wr, v3 = B*wr,
                    v4 = A*wg, v5 = B*wg, v6 = A*wq, v7 = B*wq;
        float* dr = &diff[wv][0][0];
        if (B != 0.f) {
            const float tk  = -A / B;
            const bool  pos = (B > 0.f);
            // pos: k = count(d <= tk)  -> active suffix [k,256)
            // neg: k = count(d <  tk)  -> active prefix [0,k)
            // 9 guarded steps so k can reach the full range [0,256]
            int k = 0;
#pragma unroll
            for (int s = 256; s >= 1; s >>= 1) {
                const int nk = k + s;
                if (nk <= NS) {
                    const float dv = sdep[wv][nk - 1];
                    const bool  le = pos ? (dv <= tk) : (dv < tk);
                    if (le) k = nk;
                }
            }
            if (pos) {                                // activate at k (slot 256 = never, absorbed by pad)
                atomicAdd(dr + 0*NSP + k, v0);
                atomicAdd(dr + 1*NSP + k, v1);
                atomicAdd(dr + 2*NSP + k, v2);
                atomicAdd(dr + 3*NSP + k, v3);
                atomicAdd(dr + 4*NSP + k, v4);
                atomicAdd(dr + 5*NSP + k, v5);
                atomicAdd(dr + 6*NSP + k, v6);
                atomicAdd(dr + 7*NSP + k, v7);
            } else {                                  // active from 0, deactivate at k
                atomicAdd(dr + 0*NSP, v0);
                atomicAdd(dr + 1*NSP, v1);
                atomicAdd(dr + 2*NSP, v2);
                atomicAdd(dr + 3*NSP, v3);
                atomicAdd(dr + 4*NSP, v4);
                atomicAdd(dr + 5*NSP, v5);
                atomicAdd(dr + 6*NSP, v6);
                atomicAdd(dr + 7*NSP, v7);
                atomicAdd(dr + 0*NSP + k, -v0);
                atomicAdd(dr + 1*NSP + k, -v1);
                atomicAdd(dr + 2*NSP + k, -v2);
                atomicAdd(dr + 3*NSP + k, -v3);
                atomicAdd(dr + 4*NSP + k, -v4);
                atomicAdd(dr + 5*NSP + k, -v5);
                atomicAdd(dr + 6*NSP + k, -v6);
                atomicAdd(dr + 7*NSP + k, -v7);
            }
        } else if (A > 0.f) {                         // constant-active unit (B-parts are 0)
            atomicAdd(dr + 0*NSP, v0);
            atomicAdd(dr + 2*NSP, v2);
            atomicAdd(dr + 4*NSP, v4);
            atomicAdd(dr + 6*NSP, v6);
        }
    }
    __syncthreads();

    // ---- phase C: 8-channel inclusive scans over the 256 sample slots ----
    float ch[8][4];
#pragma unroll
    for (int c = 0; c < 8; ++c) {
        const float4 dv = ((const float4*)&diff[wv][c][0])[lane];
        const float p0 = dv.x, p1 = p0 + dv.y, p2 = p1 + dv.z, p3 = p2 + dv.w;
        float incl = p3;
#pragma unroll
        for (int off = 1; off < 64; off <<= 1) {
            const float u = __shfl_up(incl, off, 64);
            if (lane >= off) incl += u;
        }
        const float base = incl - p3;
        ch[c][0] = base + p0; ch[c][1] = base + p1;
        ch[c][2] = base + p2; ch[c][3] = base + p3;
    }

    // ---- phase D: per-sample epilogue ----
    const float dpt[4] = {dep.x, dep.y, dep.z, dep.w};
    const float dsv[4] = {dst.x, dst.y, dst.z, dst.w};
    const int  vid[4]  = {vidx.x, vidx.y, vidx.z, vidx.w};

    float crj[4], cgj[4], cbj[4], c4[4];
    float run = 0.f;
#pragma unroll
    for (int j = 0; j < 4; ++j) {
        const float sg = fmaf(dpt[j], ch[1][j], ch[0][j]);
        crj[j] = fmaf(dpt[j], ch[3][j], ch[2][j]);
        cgj[j] = fmaf(dpt[j], ch[5][j], ch[4][j]);
        cbj[j] = fmaf(dpt[j], ch[7][j], ch[6][j]);
        float f = fmaxf(sg, 0.f) * dsv[j] * 7.0f;
        if (vid[j] == -1) f = 0.f;
        run += f;
        c4[j] = run;
    }

    // wave-level exclusive scan of per-thread free-energy totals
    float tot = run;
#pragma unroll
    for (int off = 1; off < 64; off <<= 1) {
        const float v = __shfl_up(tot, off, 64);
        if (lane >= off) tot += v;
    }
    const float base2 = tot - run;

    // telescoped probs: p[j] = exp(-(base2+c[j-1])) - exp(-(base2+c[j]))
    float Eprev = __expf(-base2);
    float prob[4];
    float s0 = 0.f, s1 = 0.f, s2 = 0.f, s3 = 0.f, s4 = 0.f;
#pragma unroll
    for (int j = 0; j < 4; ++j) {
        const float Ej = __expf(-(base2 + c4[j]));
        const float p  = Eprev - Ej;
        Eprev = Ej;
        prob[j] = p;
        const float rr = __builtin_amdgcn_rcpf(1.f + __expf(-(crj[j] + dwr)));
        const float gg = __builtin_amdgcn_rcpf(1.f + __expf(-(cgj[j] + dwg)));
        const float bb = __builtin_amdgcn_rcpf(1.f + __expf(-(cbj[j] + dwb)));
        s0 += p;
        s1 = fmaf(dpt[j], p, s1);
        s2 = fmaf(rr, p, s2);
        s3 = fmaf(gg, p, s3);
        s4 = fmaf(bb, p, s4);
    }

    // wave reduction of the 5 sums
#pragma unroll
    for (int off = 32; off >= 1; off >>= 1) {
        s0 += __shfl_xor(s0, off, 64);
        s1 += __shfl_xor(s1, off, 64);
        s2 += __shfl_xor(s2, off, 64);
        s3 += __shfl_xor(s3, off, 64);
        s4 += __shfl_xor(s4, off, 64);
    }

    float* orow = out + (size_t)ray * (NS + 5);
#pragma unroll
    for (int j = 0; j < 4; ++j)
        orow[5 + 4*lane + j] = prob[j];

    if (lane == 0) {
        orow[0] = s2;          // r
        orow[1] = s3;          // g
        orow[2] = s4;          // b
        orow[3] = s1;          // depth
        orow[4] = 1.f - s0;    // missed
    }
}

extern "C" void kernel_launch(void* const* d_in, const int* in_sizes, int n_in,
                              void* d_out, int out_size, void* d_ws, size_t ws_size,
                              hipStream_t stream)
{
    vr_kernel<<<NRAYS / RPB, 256, 0, stream>>>(
        (const float*)d_in[0],   // ray_start
        (const float*)d_in[1],   // ray_dir
        (const float*)d_in[2],   // sampled_depth
        (const float*)d_in[3],   // sampled_dists
        (const int*)  d_in[4],   // sampled_idx
        (const float*)d_in[5],   // W1
        (const float*)d_in[6],   // b1
        (const float*)d_in[7],   // w_sigma
        (const float*)d_in[8],   // W_rgb
        (const float*)d_in[9],   // W_dir
        (const float*)d_in[10],  // b_rgb
        (float*)d_out);
}

// Round 7
// 110.799 us; speedup vs baseline: 1.2801x; 1.2801x over previous
//
#include <hip/hip_runtime.h>

#define NRAYS 8192
#define NS    256
#define HID   64
#define RPB   16     // rays per block: 4 waves x 4 quarter-waves
#define SPT   16     // samples per thread (16 lanes cover 256 samples)

typedef float v2f __attribute__((ext_vector_type(2)));
static __device__ __forceinline__ v2f splat2(float s) { v2f v; v.x = s; v.y = s; return v; }

__global__ __launch_bounds__(256) void vr_kernel(
    const float* __restrict__ ray_start,
    const float* __restrict__ ray_dir,
    const float* __restrict__ sampled_depth,
    const float* __restrict__ sampled_dists,
    const int*   __restrict__ sampled_idx,
    const float* __restrict__ W1,
    const float* __restrict__ b1,
    const float* __restrict__ w_sigma,
    const float* __restrict__ W_rgb,
    const float* __restrict__ W_dir,
    const float* __restrict__ b_rgb,
    float* __restrict__ out)
{
    // sW[h]     = {w_sigma[h], W_rgb[h][0], W_rgb[h][1], W_rgb[h][2]}  (block-shared)
    // sAB[r][h] = {A, B} with hv(h,d) = relu(A + d*B)                  (per-ray)
    __shared__ float4 sW[HID];
    __shared__ float2 sAB[RPB][HID];

    const int t = threadIdx.x;
    if (t < HID)
        sW[t] = make_float4(w_sigma[t], W_rgb[t*3+0], W_rgb[t*3+1], W_rgb[t*3+2]);

#pragma unroll
    for (int p = 0; p < 4; ++p) {
        const int idx = t + p * 256;        // 1024 (ray,h) pairs
        const int r   = idx >> 6;
        const int h   = idx & 63;
        const int ray = blockIdx.x * RPB + r;
        const float ox = ray_start[ray*3+0], oy = ray_start[ray*3+1], oz = ray_start[ray*3+2];
        const float dx = ray_dir[ray*3+0],  dy = ray_dir[ray*3+1],  dz = ray_dir[ray*3+2];
        const float w0 = W1[h], w1 = W1[HID + h], w2 = W1[2*HID + h];
        const float A = fmaf(w0, ox, fmaf(w1, oy, fmaf(w2, oz, b1[h])));
        const float B = fmaf(w0, dx, fmaf(w1, dy, w2 * dz));
        sAB[r][h] = make_float2(A, B);
    }
    __syncthreads();

    const int lane = t & 63;
    const int wv   = t >> 6;
    const int ql   = lane & 15;                 // position within quarter-wave
    const int rs   = wv * 4 + (lane >> 4);      // ray slot in block
    const int ray  = blockIdx.x * RPB + rs;

    // per-ray view-dependent rgb bias (uniform across the quarter-wave)
    const float dx = ray_dir[ray*3+0], dy = ray_dir[ray*3+1], dz = ray_dir[ray*3+2];
    const float dwr = fmaf(dx, W_dir[0], fmaf(dy, W_dir[3], fmaf(dz, W_dir[6], b_rgb[0])));
    const float dwg = fmaf(dx, W_dir[1], fmaf(dy, W_dir[4], fmaf(dz, W_dir[7], b_rgb[1])));
    const float dwb = fmaf(dx, W_dir[2], fmaf(dy, W_dir[5], fmaf(dz, W_dir[8], b_rgb[2])));

    // this thread owns samples SPT*ql .. SPT*ql+15 (contiguous)
    const size_t rbase = (size_t)ray * NS + (size_t)ql * SPT;
    float dpt[SPT], dsv[SPT];
    int   vid[SPT];
#pragma unroll
    for (int i = 0; i < 4; ++i) {
        const float4 d4 = ((const float4*)(sampled_depth + rbase))[i];
        const float4 s4 = ((const float4*)(sampled_dists + rbase))[i];
        const int4   i4 = ((const int4*)(sampled_idx + rbase))[i];
        dpt[4*i+0] = d4.x; dpt[4*i+1] = d4.y; dpt[4*i+2] = d4.z; dpt[4*i+3] = d4.w;
        dsv[4*i+0] = s4.x; dsv[4*i+1] = s4.y; dsv[4*i+2] = s4.z; dsv[4*i+3] = s4.w;
        vid[4*i+0] = i4.x; vid[4*i+1] = i4.y; vid[4*i+2] = i4.z; vid[4*i+3] = i4.w;
    }

    v2f d2[8];
#pragma unroll
    for (int i = 0; i < 8; ++i) { d2[i].x = dpt[2*i]; d2[i].y = dpt[2*i+1]; }

    const v2f zero2 = splat2(0.f);
    v2f sg2[8], cr2[8], cg2[8], cb2[8];
#pragma unroll
    for (int i = 0; i < 8; ++i) { sg2[i] = zero2; cr2[i] = zero2; cg2[i] = zero2; cb2[i] = zero2; }

#pragma unroll 8
    for (int h = 0; h < HID; ++h) {
        const float4 w  = sW[h];           // broadcast (same addr, free)
        const float2 ab = sAB[rs][h];      // 4 distinct addrs per wave
        const v2f a2  = splat2(ab.x);
        const v2f b2  = splat2(ab.y);
        const v2f ws2 = splat2(w.x);
        const v2f wr2 = splat2(w.y);
        const v2f wg2 = splat2(w.z);
        const v2f wq2 = splat2(w.w);
#pragma unroll
        for (int i = 0; i < 8; ++i) {
            v2f hv = __builtin_elementwise_fma(b2, d2[i], a2);
            hv = __builtin_elementwise_max(hv, zero2);         // relu
            sg2[i] = __builtin_elementwise_fma(hv, ws2, sg2[i]);
            cr2[i] = __builtin_elementwise_fma(hv, wr2, cr2[i]);
            cg2[i] = __builtin_elementwise_fma(hv, wg2, cg2[i]);
            cb2[i] = __builtin_elementwise_fma(hv, wq2, cb2[i]);
        }
    }

    // free energy + thread-local inclusive scan over 16 samples
    float c[SPT];
    float run = 0.f;
#pragma unroll
    for (int j = 0; j < SPT; ++j) {
        const float sg = (j & 1) ? sg2[j>>1].y : sg2[j>>1].x;
        float f = fmaxf(sg, 0.f) * dsv[j] * 7.0f;
        if (vid[j] == -1) f = 0.f;
        run += f;
        c[j] = run;
    }

    // quarter-wave (width 16) exclusive scan of per-thread totals
    float tot = run;
#pragma unroll
    for (int off = 1; off < 16; off <<= 1) {
        const float v = __shfl_up(tot, off, 16);
        if (ql >= off) tot += v;
    }
    const float base = tot - run;

    // telescoped probs: p[j] = exp(-(base+c[j-1])) - exp(-(base+c[j]))
    float Eprev = __expf(-base);
    float prob[SPT];
    float s0 = 0.f, s1 = 0.f, s2 = 0.f, s3 = 0.f, s4 = 0.f;
#pragma unroll
    for (int j = 0; j < SPT; ++j) {
        const float Ej = __expf(-(base + c[j]));
        const float p  = Eprev - Ej;
        Eprev = Ej;
        prob[j] = p;
        const float lr = (j & 1) ? cr2[j>>1].y : cr2[j>>1].x;
        const float lg = (j & 1) ? cg2[j>>1].y : cg2[j>>1].x;
        const float lb = (j & 1) ? cb2[j>>1].y : cb2[j>>1].x;
        const float rr = __builtin_amdgcn_rcpf(1.f + __expf(-(lr + dwr)));
        const float gg = __builtin_amdgcn_rcpf(1.f + __expf(-(lg + dwg)));
        const float bb = __builtin_amdgcn_rcpf(1.f + __expf(-(lb + dwb)));
        s0 += p;
        s1 = fmaf(dpt[j], p, s1);
        s2 = fmaf(rr, p, s2);
        s3 = fmaf(gg, p, s3);
        s4 = fmaf(bb, p, s4);
    }

    // quarter-wave reduction of the 5 sums
#pragma unroll
    for (int off = 8; off >= 1; off >>= 1) {
        s0 += __shfl_xor(s0, off, 16);
        s1 += __shfl_xor(s1, off, 16);
        s2 += __shfl_xor(s2, off, 16);
        s3 += __shfl_xor(s3, off, 16);
        s4 += __shfl_xor(s4, off, 16);
    }

    float* orow = out + (size_t)ray * (NS + 5);
#pragma unroll
    for (int j = 0; j < SPT; ++j)
        orow[5 + SPT*ql + j] = prob[j];

    if (ql == 0) {
        orow[0] = s2;          // r
        orow[1] = s3;          // g
        orow[2] = s4;          // b
        orow[3] = s1;          // depth
        orow[4] = 1.f - s0;    // missed
    }
}

extern "C" void kernel_launch(void* const* d_in, const int* in_sizes, int n_in,
                              void* d_out, int out_size, void* d_ws, size_t ws_size,
                              hipStream_t stream)
{
    vr_kernel<<<NRAYS / RPB, 256, 0, stream>>>(
        (const float*)d_in[0],   // ray_start
        (const float*)d_in[1],   // ray_dir
        (const float*)d_in[2],   // sampled_depth
        (const float*)d_in[3],   // sampled_dists
        (const int*)  d_in[4],   // sampled_idx
        (const float*)d_in[5],   // W1
        (const float*)d_in[6],   // b1
        (const float*)d_in[7],   // w_sigma
        (const float*)d_in[8],   // W_rgb
        (const float*)d_in[9],   // W_dir
        (const float*)d_in[10],  // b_rgb
        (float*)d_out);
}